// Round 3
// baseline (516.882 us; speedup 1.0000x reference)
//
#include <hip/hip_runtime.h>

typedef unsigned short ushort_t;

static __device__ __forceinline__ float bf2f(ushort_t u) {
  union { unsigned int i; float f; } v; v.i = ((unsigned int)u) << 16; return v.f;
}
static __device__ __forceinline__ ushort_t f2bf(float f) {
  union { float f; unsigned int i; } v; v.f = f;
  unsigned int r = v.i + 0x7FFFu + ((v.i >> 16) & 1u);
  return (ushort_t)(r >> 16);
}
static __device__ __forceinline__ float leaky(float s) {
  return s > 0.f ? s : 0.2f * s;
}

// ---------------------------------------------------------------------------
// Kernel A: h = feat @ W  (fp32 in, fp32 acc) -> bf16 h, fp32 el/er per node.
// 16 nodes per 256-thread block; W (32KB) + feat tile (8KB) staged in LDS.
// wave w handles nodes w*4..w*4+3; lane c = output column (head*16+f).
// ---------------------------------------------------------------------------
__global__ __launch_bounds__(256) void gat_linear(
    const float* __restrict__ feat, const float* __restrict__ W,
    const float* __restrict__ attnl, const float* __restrict__ attnr,
    ushort_t* __restrict__ h_out, float* __restrict__ el, float* __restrict__ er,
    int N)
{
  __shared__ float sW[128 * 64];   // 32 KB, layout [k][c]
  __shared__ float sF[16 * 128];   // 8 KB, layout [node][k]
  const int t = threadIdx.x;
  const int b = blockIdx.x;

  const float4* gW = (const float4*)W;
  float4* sW4 = (float4*)sW;
  #pragma unroll
  for (int i = 0; i < 8; ++i) sW4[i * 256 + t] = gW[i * 256 + t];

  const float4* gF = (const float4*)(feat + (size_t)b * 16 * 128);
  float4* sF4 = (float4*)sF;
  #pragma unroll
  for (int i = 0; i < 2; ++i) {
    float4 v = make_float4(0.f, 0.f, 0.f, 0.f);
    if ((size_t)b * 2048 + (size_t)(i * 256 + t) * 4 + 4 <= (size_t)N * 128)
      v = gF[i * 256 + t];
    sF4[i * 256 + t] = v;
  }
  __syncthreads();

  const int w = t >> 6, c = t & 63;
  const int l0 = w * 4;
  const float al = attnl[c];
  const float ar = attnr[c];

  float acc[4] = {0.f, 0.f, 0.f, 0.f};
  for (int kc = 0; kc < 16; ++kc) {
    float wv[8];
    #pragma unroll
    for (int kk = 0; kk < 8; ++kk) wv[kk] = sW[(kc * 8 + kk) * 64 + c];
    #pragma unroll
    for (int j = 0; j < 4; ++j) {
      const float* fr = &sF[(l0 + j) * 128 + kc * 8];
      #pragma unroll
      for (int kk = 0; kk < 8; ++kk) acc[j] += fr[kk] * wv[kk];
    }
  }

  #pragma unroll
  for (int j = 0; j < 4; ++j) {
    const int nj = b * 16 + l0 + j;
    if (nj >= N) continue;
    h_out[(size_t)nj * 64 + c] = f2bf(acc[j]);
    float evl = acc[j] * al;
    float evr = acc[j] * ar;
    #pragma unroll
    for (int off = 8; off >= 1; off >>= 1) {
      evl += __shfl_xor(evl, off, 16);
      evr += __shfl_xor(evr, off, 16);
    }
    if ((c & 15) == 0) {
      el[nj * 4 + (c >> 4)] = evl;
      er[nj * 4 + (c >> 4)] = evr;
    }
  }
}

// ---------------------------------------------------------------------------
// Kernel B: per-edge scores -> per-block max; target-degree histogram.
// ---------------------------------------------------------------------------
__global__ __launch_bounds__(256) void gat_edge(
    const int* __restrict__ src, const int* __restrict__ trg,
    const float4* __restrict__ el4, const float4* __restrict__ er4,
    int* __restrict__ deg, float* __restrict__ blockmax, int E)
{
  const int e = blockIdx.x * 256 + threadIdx.x;
  float m = -1e30f;
  if (e < E) {
    const int si = src[e], ti = trg[e];
    const float4 a = el4[si];
    const float4 bb = er4[ti];
    float sx = leaky(a.x + bb.x);
    float sy = leaky(a.y + bb.y);
    float sz = leaky(a.z + bb.z);
    float sw = leaky(a.w + bb.w);
    m = fmaxf(fmaxf(sx, sy), fmaxf(sz, sw));
    atomicAdd(&deg[ti], 1);
  }
  #pragma unroll
  for (int off = 32; off >= 1; off >>= 1) m = fmaxf(m, __shfl_xor(m, off, 64));
  __shared__ float wm[4];
  if ((threadIdx.x & 63) == 0) wm[threadIdx.x >> 6] = m;
  __syncthreads();
  if (threadIdx.x == 0)
    blockmax[blockIdx.x] = fmaxf(fmaxf(wm[0], wm[1]), fmaxf(wm[2], wm[3]));
}

__global__ __launch_bounds__(1024) void gat_max(
    const float* __restrict__ bm, int n, float* __restrict__ gmax)
{
  float m = -1e30f;
  for (int i = threadIdx.x; i < n; i += 1024) m = fmaxf(m, bm[i]);
  #pragma unroll
  for (int off = 32; off >= 1; off >>= 1) m = fmaxf(m, __shfl_xor(m, off, 64));
  __shared__ float wm[16];
  const int w = threadIdx.x >> 6;
  if ((threadIdx.x & 63) == 0) wm[w] = m;
  __syncthreads();
  if (threadIdx.x == 0) {
    float r = wm[0];
    for (int i = 1; i < 16; ++i) r = fmaxf(r, wm[i]);
    gmax[0] = r;
  }
}

// ---------------------------------------------------------------------------
// Hierarchical exclusive scan of deg -> rowoff[N+1]
// ---------------------------------------------------------------------------
__global__ __launch_bounds__(256) void scan_part(
    const int* __restrict__ deg, int* __restrict__ partial, int N)
{
  const int i = blockIdx.x * 256 + threadIdx.x;
  int v = (i < N) ? deg[i] : 0;
  #pragma unroll
  for (int off = 32; off >= 1; off >>= 1) v += __shfl_xor(v, off, 64);
  __shared__ int wv[4];
  if ((threadIdx.x & 63) == 0) wv[threadIdx.x >> 6] = v;
  __syncthreads();
  if (threadIdx.x == 0) partial[blockIdx.x] = wv[0] + wv[1] + wv[2] + wv[3];
}

__global__ __launch_bounds__(512) void scan_top(
    const int* __restrict__ partial, int n, int* __restrict__ bpref)
{
  const int t = threadIdx.x;
  const int lane = t & 63, w = t >> 6;
  int v = (t < n) ? partial[t] : 0;
  const int orig = v;
  #pragma unroll
  for (int d = 1; d < 64; d <<= 1) {
    int u = __shfl_up(v, d, 64);
    if (lane >= d) v += u;
  }
  __shared__ int ws[8];
  if (lane == 63) ws[w] = v;
  __syncthreads();
  int off = 0;
  for (int i = 0; i < w; ++i) off += ws[i];
  if (t < n) bpref[t] = off + v - orig;
}

__global__ __launch_bounds__(256) void scan_final(
    const int* __restrict__ deg, const int* __restrict__ bpref,
    int* __restrict__ rowoff, int N)
{
  const int i = blockIdx.x * 256 + threadIdx.x;
  const int lane = threadIdx.x & 63, w = threadIdx.x >> 6;
  int v = (i < N) ? deg[i] : 0;
  const int orig = v;
  #pragma unroll
  for (int d = 1; d < 64; d <<= 1) {
    int u = __shfl_up(v, d, 64);
    if (lane >= d) v += u;
  }
  __shared__ int ws[4];
  if (lane == 63) ws[w] = v;
  __syncthreads();
  int off = 0;
  for (int j = 0; j < w; ++j) off += ws[j];
  const int excl = bpref[blockIdx.x] + off + v - orig;
  if (i <= N) rowoff[i] = excl;
}

// ---------------------------------------------------------------------------
// Counting-sort edges by target; store SOURCE node id (edge id not needed).
// ---------------------------------------------------------------------------
__global__ __launch_bounds__(256) void gat_scatter(
    const int* __restrict__ src, const int* __restrict__ trg,
    const int* __restrict__ rowoff, int* __restrict__ cursor,
    int* __restrict__ csrsrc, int E)
{
  const int e = blockIdx.x * 256 + threadIdx.x;
  if (e >= E) return;
  const int ti = trg[e];
  const int pos = atomicAdd(&cursor[ti], 1);
  csrsrc[rowoff[ti] + pos] = src[e];
}

// ---------------------------------------------------------------------------
// Aggregation: one wave per target node. Single pass:
//   acc[l] += h[src][l] * p,  dacc += p,  out = acc / (dacc + eps)
// (normalization is a constant per (node,head) -> divide after the sum)
// Output is FLOAT32 (reference output dtype).
// ---------------------------------------------------------------------------
__global__ __launch_bounds__(256) void gat_agg(
    const int* __restrict__ csrsrc, const int* __restrict__ rowoff,
    const float* __restrict__ el, const float* __restrict__ er,
    const ushort_t* __restrict__ hbf, const float* __restrict__ gmax,
    float* __restrict__ out, int N)
{
  const int l = threadIdx.x & 63;
  const int n = blockIdx.x * 4 + (threadIdx.x >> 6);
  if (n >= N) return;
  const int hd = l >> 4;
  const int start = rowoff[n];
  const int end = rowoff[n + 1];
  const float M = gmax[0];
  const float ern = er[n * 4 + hd];

  float acc = 0.f, dacc = 0.f;
  for (int base = start; base < end; base += 64) {
    const int cnt = min(64, end - base);
    int sn = 0;
    if (l < cnt) sn = csrsrc[base + l];
    for (int j = 0; j < cnt; ++j) {
      const int snj = __shfl(sn, j, 64);
      const float s = leaky(el[snj * 4 + hd] + ern);
      const float p = __expf(s - M);
      dacc += p;
      acc += bf2f(hbf[(size_t)snj * 64 + l]) * p;
    }
  }
  out[(size_t)n * 64 + l] = acc / (dacc + 1e-16f);
}

// ---------------------------------------------------------------------------
extern "C" void kernel_launch(void* const* d_in, const int* in_sizes, int n_in,
                              void* d_out, int out_size, void* d_ws, size_t ws_size,
                              hipStream_t stream) {
  const float* feat  = (const float*)d_in[0];
  const float* W     = (const float*)d_in[1];
  const float* attnl = (const float*)d_in[2];
  const float* attnr = (const float*)d_in[3];
  const int* src = (const int*)d_in[4];
  const int* trg = (const int*)d_in[5];
  float* out = (float*)d_out;

  const int N = in_sizes[0] / 128;  // 100000
  const int E = in_sizes[4];        // 1600000

  char* p = (char*)d_ws;
  auto take = [&](size_t bytes) -> char* {
    char* r = p;
    p += (bytes + 255) & ~(size_t)255;
    return r;
  };
  ushort_t* h_bf  = (ushort_t*)take((size_t)N * 64 * 2); // 12.8 MB
  float* el       = (float*)take((size_t)N * 16);        // 1.6 MB
  float* er       = (float*)take((size_t)N * 16);        // 1.6 MB
  int* deg        = (int*)take((size_t)N * 4);
  int* rowoff     = (int*)take((size_t)(N + 1) * 4);
  int* cursor     = (int*)take((size_t)N * 4);
  int* csrsrc     = (int*)take((size_t)E * 4);           // 6.4 MB
  const int nbE = (E + 255) / 256;                       // 6250
  const int nbS = (N + 255) / 256;                       // 391
  float* blockmax = (float*)take((size_t)nbE * 4);
  float* gmax     = (float*)take(256);
  int* partial    = (int*)take((size_t)nbS * 4);
  int* bpref      = (int*)take((size_t)nbS * 4);

  hipMemsetAsync(deg, 0, (size_t)N * 4, stream);
  hipMemsetAsync(cursor, 0, (size_t)N * 4, stream);

  gat_linear<<<(N + 15) / 16, 256, 0, stream>>>(feat, W, attnl, attnr,
                                                h_bf, el, er, N);
  gat_edge<<<nbE, 256, 0, stream>>>(src, trg, (const float4*)el,
                                    (const float4*)er, deg, blockmax, E);
  gat_max<<<1, 1024, 0, stream>>>(blockmax, nbE, gmax);
  scan_part<<<nbS, 256, 0, stream>>>(deg, partial, N);
  scan_top<<<1, 512, 0, stream>>>(partial, nbS, bpref);
  scan_final<<<nbS, 256, 0, stream>>>(deg, bpref, rowoff, N);
  gat_scatter<<<nbE, 256, 0, stream>>>(src, trg, rowoff, cursor, csrsrc, E);
  gat_agg<<<(N + 3) / 4, 256, 0, stream>>>(csrsrc, rowoff, el, er, h_bf,
                                           gmax, out, N);
}

// Round 4
// 507.150 us; speedup vs baseline: 1.0192x; 1.0192x over previous
//
#include <hip/hip_runtime.h>

typedef unsigned short ushort_t;
typedef __attribute__((ext_vector_type(8))) short bf16x8;
typedef __attribute__((ext_vector_type(4))) float f32x4v;

static __device__ __forceinline__ float bf2f(ushort_t u) {
  union { unsigned int i; float f; } v; v.i = ((unsigned int)u) << 16; return v.f;
}
static __device__ __forceinline__ ushort_t f2bf(float f) {
  union { float f; unsigned int i; } v; v.f = f;
  unsigned int r = v.i + 0x7FFFu + ((v.i >> 16) & 1u);
  return (ushort_t)(r >> 16);
}
static __device__ __forceinline__ short f2bfs(float f) {
  return (short)f2bf(f);
}
static __device__ __forceinline__ float leaky(float s) {
  return s > 0.f ? s : 0.2f * s;
}
// order-preserving float<->uint map (memset-0 is identity: all finite floats map > 0)
static __device__ __forceinline__ unsigned int flipf(float f) {
  unsigned int u = __float_as_uint(f);
  return (u & 0x80000000u) ? ~u : (u | 0x80000000u);
}
static __device__ __forceinline__ float unflipf(unsigned int u) {
  u = (u & 0x80000000u) ? (u & 0x7FFFFFFFu) : ~u;
  return __uint_as_float(u);
}

// ---------------------------------------------------------------------------
// Pack W (fp32 [128][64]) into bf16 B-fragments for mfma_f32_16x16x32_bf16.
// wfrag[((w*4+kc)*64 + lane)*8 + j] = bf16(W[kc*32 + (lane>>4)*8 + j][w*16 + (lane&15)])
// One block, 256 threads. 16 KB output -> L2-resident for gat_linear.
// ---------------------------------------------------------------------------
__global__ __launch_bounds__(256) void gat_packw(
    const float* __restrict__ W, ushort_t* __restrict__ wfrag)
{
  const int t = threadIdx.x;
  const int w = t >> 6, l = t & 63;
  const int q = l >> 4, n = l & 15;
  #pragma unroll
  for (int kc = 0; kc < 4; ++kc) {
    #pragma unroll
    for (int j = 0; j < 8; ++j) {
      const int k = kc * 32 + q * 8 + j;
      wfrag[(((w * 4 + kc) * 64) + l) * 8 + j] = f2bf(W[k * 64 + w * 16 + n]);
    }
  }
}

// ---------------------------------------------------------------------------
// Kernel A (MFMA): h = feat @ W -> bf16 h, fp32 el/er, node-wise el/er maxima.
// 16 nodes per 256-thread block; wave w computes cols [w*16, w*16+16) = head w.
// A-frag: A[m=lane&15][k=quad*8+j]; C/D: col=lane&15, row=quad*4+reg.
// ---------------------------------------------------------------------------
__global__ __launch_bounds__(256) void gat_linear(
    const float* __restrict__ feat, const ushort_t* __restrict__ wfrag,
    const float* __restrict__ attnl, const float* __restrict__ attnr,
    ushort_t* __restrict__ h_out, float* __restrict__ el, float* __restrict__ er,
    unsigned int* __restrict__ gmax2, int N)
{
  __shared__ float sF[16 * 132];   // 16 rows, padded stride 132 floats (8.4 KB)
  __shared__ unsigned int smax[2];
  const int t = threadIdx.x;
  const int b = blockIdx.x;
  const int w = t >> 6, l = t & 63;
  const int q = l >> 4, m = l & 15;

  if (t < 2) smax[t] = 0;

  // B-fragments: 4 K-chunks x 16 B per lane, from L2-resident packed W
  bf16x8 bfr[4];
  #pragma unroll
  for (int kc = 0; kc < 4; ++kc)
    bfr[kc] = *(const bf16x8*)(wfrag + (((w * 4 + kc) * 64) + l) * 8);

  const float al = attnl[w * 16 + m];
  const float ar = attnr[w * 16 + m];

  // stage feat tile (16 x 128 fp32) coalesced into padded LDS
  const float4* gF = (const float4*)(feat + (size_t)b * 16 * 128);
  #pragma unroll
  for (int i = 0; i < 2; ++i) {
    const int idx = i * 256 + t;          // 0..511 float4s
    const int node = idx >> 5, off = idx & 31;
    float4 v = make_float4(0.f, 0.f, 0.f, 0.f);
    if (b * 16 + node < N) v = gF[idx];
    *(float4*)(sF + node * 132 + off * 4) = v;
  }
  __syncthreads();

  // K loop: LDS fp32 -> bf16 A-frag -> MFMA
  f32x4v acc = {0.f, 0.f, 0.f, 0.f};
  const float* arow = sF + m * 132 + q * 8;
  #pragma unroll
  for (int kc = 0; kc < 4; ++kc) {
    const float4 a0 = *(const float4*)(arow + kc * 32);
    const float4 a1 = *(const float4*)(arow + kc * 32 + 4);
    bf16x8 af;
    af[0] = f2bfs(a0.x); af[1] = f2bfs(a0.y);
    af[2] = f2bfs(a0.z); af[3] = f2bfs(a0.w);
    af[4] = f2bfs(a1.x); af[5] = f2bfs(a1.y);
    af[6] = f2bfs(a1.z); af[7] = f2bfs(a1.w);
    acc = __builtin_amdgcn_mfma_f32_16x16x32_bf16(af, bfr[kc], acc, 0, 0, 0);
  }

  // epilogue: h store, el/er (16-lane reductions), block maxima
  float mel = -1e30f, mer = -1e30f;
  #pragma unroll
  for (int r = 0; r < 4; ++r) {
    const int node = q * 4 + r;
    const int gn = b * 16 + node;
    const float hv = acc[r];
    float evl = hv * al;
    float evr = hv * ar;
    #pragma unroll
    for (int off = 8; off >= 1; off >>= 1) {
      evl += __shfl_xor(evl, off, 16);
      evr += __shfl_xor(evr, off, 16);
    }
    if (gn < N) {
      h_out[(size_t)gn * 64 + w * 16 + m] = f2bf(hv);
      if (m == 0) {
        el[gn * 4 + w] = evl;
        er[gn * 4 + w] = evr;
      }
    }
    mel = fmaxf(mel, evl);
    mer = fmaxf(mer, evr);
  }
  // cross-quad wave max (every lane already holds its quad's value)
  mel = fmaxf(mel, __shfl_xor(mel, 16, 64));
  mel = fmaxf(mel, __shfl_xor(mel, 32, 64));
  mer = fmaxf(mer, __shfl_xor(mer, 16, 64));
  mer = fmaxf(mer, __shfl_xor(mer, 32, 64));
  if (l == 0) {
    atomicMax(&smax[0], flipf(mel));
    atomicMax(&smax[1], flipf(mer));
  }
  __syncthreads();
  if (t == 0) {
    atomicMax(&gmax2[0], smax[0]);
    atomicMax(&gmax2[1], smax[1]);
  }
}

// ---------------------------------------------------------------------------
// Target-degree histogram (only job left for the edge pass).
// ---------------------------------------------------------------------------
__global__ __launch_bounds__(256) void gat_deg(
    const int* __restrict__ trg, int* __restrict__ deg, int E)
{
  const int e = blockIdx.x * 256 + threadIdx.x;
  if (e < E) atomicAdd(&deg[trg[e]], 1);
}

// ---------------------------------------------------------------------------
// Hierarchical exclusive scan of deg -> rowoff[N+1]
// ---------------------------------------------------------------------------
__global__ __launch_bounds__(256) void scan_part(
    const int* __restrict__ deg, int* __restrict__ partial, int N)
{
  const int i = blockIdx.x * 256 + threadIdx.x;
  int v = (i < N) ? deg[i] : 0;
  #pragma unroll
  for (int off = 32; off >= 1; off >>= 1) v += __shfl_xor(v, off, 64);
  __shared__ int wv[4];
  if ((threadIdx.x & 63) == 0) wv[threadIdx.x >> 6] = v;
  __syncthreads();
  if (threadIdx.x == 0) partial[blockIdx.x] = wv[0] + wv[1] + wv[2] + wv[3];
}

__global__ __launch_bounds__(512) void scan_top(
    const int* __restrict__ partial, int n, int* __restrict__ bpref)
{
  const int t = threadIdx.x;
  const int lane = t & 63, w = t >> 6;
  int v = (t < n) ? partial[t] : 0;
  const int orig = v;
  #pragma unroll
  for (int d = 1; d < 64; d <<= 1) {
    int u = __shfl_up(v, d, 64);
    if (lane >= d) v += u;
  }
  __shared__ int ws[8];
  if (lane == 63) ws[w] = v;
  __syncthreads();
  int off = 0;
  for (int i = 0; i < w; ++i) off += ws[i];
  if (t < n) bpref[t] = off + v - orig;
}

__global__ __launch_bounds__(256) void scan_final(
    const int* __restrict__ deg, const int* __restrict__ bpref,
    int* __restrict__ rowoff, int N)
{
  const int i = blockIdx.x * 256 + threadIdx.x;
  const int lane = threadIdx.x & 63, w = threadIdx.x >> 6;
  int v = (i < N) ? deg[i] : 0;
  const int orig = v;
  #pragma unroll
  for (int d = 1; d < 64; d <<= 1) {
    int u = __shfl_up(v, d, 64);
    if (lane >= d) v += u;
  }
  __shared__ int ws[4];
  if (lane == 63) ws[w] = v;
  __syncthreads();
  int off = 0;
  for (int j = 0; j < w; ++j) off += ws[j];
  const int excl = bpref[blockIdx.x] + off + v - orig;
  if (i <= N) rowoff[i] = excl;
}

// ---------------------------------------------------------------------------
// Counting-sort edges by target; store SOURCE node id.
// ---------------------------------------------------------------------------
__global__ __launch_bounds__(256) void gat_scatter(
    const int* __restrict__ src, const int* __restrict__ trg,
    const int* __restrict__ rowoff, int* __restrict__ cursor,
    int* __restrict__ csrsrc, int E)
{
  const int e = blockIdx.x * 256 + threadIdx.x;
  if (e >= E) return;
  const int ti = trg[e];
  const int pos = atomicAdd(&cursor[ti], 1);
  csrsrc[rowoff[ti] + pos] = src[e];
}

// ---------------------------------------------------------------------------
// Aggregation: one wave per target node, fp32 output.
// M' = max(0, max_n el + max_n er) >= every score: softmax shift-invariant.
// ---------------------------------------------------------------------------
__global__ __launch_bounds__(256) void gat_agg(
    const int* __restrict__ csrsrc, const int* __restrict__ rowoff,
    const float* __restrict__ el, const float* __restrict__ er,
    const ushort_t* __restrict__ hbf, const unsigned int* __restrict__ gmax2,
    float* __restrict__ out, int N)
{
  const int l = threadIdx.x & 63;
  const int n = blockIdx.x * 4 + (threadIdx.x >> 6);
  if (n >= N) return;
  const int hd = l >> 4;
  const int start = rowoff[n];
  const int end = rowoff[n + 1];
  const float M = fmaxf(0.f, unflipf(gmax2[0]) + unflipf(gmax2[1]));
  const float ern = er[n * 4 + hd];

  float acc = 0.f, dacc = 0.f;
  for (int base = start; base < end; base += 64) {
    const int cnt = min(64, end - base);
    int sn = 0;
    if (l < cnt) sn = csrsrc[base + l];
    for (int j = 0; j < cnt; ++j) {
      const int snj = __shfl(sn, j, 64);
      const float s = leaky(el[snj * 4 + hd] + ern);
      const float p = __expf(s - M);
      dacc += p;
      acc += bf2f(hbf[(size_t)snj * 64 + l]) * p;
    }
  }
  out[(size_t)n * 64 + l] = acc / (dacc + 1e-16f);
}

// ---------------------------------------------------------------------------
extern "C" void kernel_launch(void* const* d_in, const int* in_sizes, int n_in,
                              void* d_out, int out_size, void* d_ws, size_t ws_size,
                              hipStream_t stream) {
  const float* feat  = (const float*)d_in[0];
  const float* W     = (const float*)d_in[1];
  const float* attnl = (const float*)d_in[2];
  const float* attnr = (const float*)d_in[3];
  const int* src = (const int*)d_in[4];
  const int* trg = (const int*)d_in[5];
  float* out = (float*)d_out;

  const int N = in_sizes[0] / 128;  // 100000
  const int E = in_sizes[4];        // 1600000

  char* p = (char*)d_ws;
  auto take = [&](size_t bytes) -> char* {
    char* r = p;
    p += (bytes + 255) & ~(size_t)255;
    return r;
  };
  ushort_t* h_bf  = (ushort_t*)take((size_t)N * 64 * 2); // 12.8 MB
  float* el       = (float*)take((size_t)N * 16);        // 1.6 MB
  float* er       = (float*)take((size_t)N * 16);        // 1.6 MB
  int* deg        = (int*)take((size_t)N * 4);
  int* rowoff     = (int*)take((size_t)(N + 1) * 4);
  int* cursor     = (int*)take((size_t)N * 4);
  int* csrsrc     = (int*)take((size_t)E * 4);           // 6.4 MB
  ushort_t* wfrag = (ushort_t*)take(4 * 4 * 64 * 8 * 2); // 16 KB
  unsigned int* gmax2 = (unsigned int*)take(256);
  const int nbE = (E + 255) / 256;                       // 6250
  const int nbS = (N + 255) / 256;                       // 391
  int* partial    = (int*)take((size_t)nbS * 4);
  int* bpref      = (int*)take((size_t)nbS * 4);

  hipMemsetAsync(deg, 0, (size_t)N * 4, stream);
  hipMemsetAsync(cursor, 0, (size_t)N * 4, stream);
  hipMemsetAsync(gmax2, 0, 8, stream);

  gat_packw<<<1, 256, 0, stream>>>(W, wfrag);
  gat_deg<<<nbE, 256, 0, stream>>>(trg, deg, E);
  gat_linear<<<(N + 15) / 16, 256, 0, stream>>>(feat, wfrag, attnl, attnr,
                                                h_bf, el, er, gmax2, N);
  scan_part<<<nbS, 256, 0, stream>>>(deg, partial, N);
  scan_top<<<1, 512, 0, stream>>>(partial, nbS, bpref);
  scan_final<<<nbS, 256, 0, stream>>>(deg, bpref, rowoff, N);
  gat_scatter<<<nbE, 256, 0, stream>>>(src, trg, rowoff, cursor, csrsrc, E);
  gat_agg<<<(N + 3) / 4, 256, 0, stream>>>(csrsrc, rowoff, el, er, h_bf,
                                           gmax2, out, N);
}

// Round 5
// 382.171 us; speedup vs baseline: 1.3525x; 1.3270x over previous
//
#include <hip/hip_runtime.h>

typedef unsigned short ushort_t;
typedef __attribute__((ext_vector_type(8))) short bf16x8;
typedef __attribute__((ext_vector_type(4))) float f32x4v;

static __device__ __forceinline__ float bf2f(ushort_t u) {
  union { unsigned int i; float f; } v; v.i = ((unsigned int)u) << 16; return v.f;
}
static __device__ __forceinline__ ushort_t f2bf(float f) {
  union { float f; unsigned int i; } v; v.f = f;
  unsigned int r = v.i + 0x7FFFu + ((v.i >> 16) & 1u);
  return (ushort_t)(r >> 16);
}
static __device__ __forceinline__ short f2bfs(float f) {
  return (short)f2bf(f);
}
static __device__ __forceinline__ float leaky(float s) {
  return s > 0.f ? s : 0.2f * s;
}

// ---------------------------------------------------------------------------
// Pack W (fp32 [128][64]) into bf16 B-fragments for mfma_f32_16x16x32_bf16.
// ---------------------------------------------------------------------------
__global__ __launch_bounds__(256) void gat_packw(
    const float* __restrict__ W, ushort_t* __restrict__ wfrag)
{
  const int t = threadIdx.x;
  const int w = t >> 6, l = t & 63;
  const int q = l >> 4, n = l & 15;
  #pragma unroll
  for (int kc = 0; kc < 4; ++kc) {
    #pragma unroll
    for (int j = 0; j < 8; ++j) {
      const int k = kc * 32 + q * 8 + j;
      wfrag[(((w * 4 + kc) * 64) + l) * 8 + j] = f2bf(W[k * 64 + w * 16 + n]);
    }
  }
}

// ---------------------------------------------------------------------------
// Kernel A (MFMA): h = feat @ W -> bf16 h, fp32 el/er, per-BLOCK el/er maxima
// (plain stores; global same-address atomics were the round-4 bottleneck).
// ---------------------------------------------------------------------------
__global__ __launch_bounds__(256) void gat_linear(
    const float* __restrict__ feat, const ushort_t* __restrict__ wfrag,
    const float* __restrict__ attnl, const float* __restrict__ attnr,
    ushort_t* __restrict__ h_out, float* __restrict__ el, float* __restrict__ er,
    float* __restrict__ blockmax2, int N)
{
  __shared__ float sF[16 * 132];   // 16 rows, padded stride 132 floats (8.4 KB)
  __shared__ float wmax[8];        // per-wave (mel, mer)
  const int t = threadIdx.x;
  const int b = blockIdx.x;
  const int w = t >> 6, l = t & 63;
  const int q = l >> 4, m = l & 15;

  // B-fragments: 4 K-chunks x 16 B per lane, from L2/L3-resident packed W
  bf16x8 bfr[4];
  #pragma unroll
  for (int kc = 0; kc < 4; ++kc)
    bfr[kc] = *(const bf16x8*)(wfrag + (((w * 4 + kc) * 64) + l) * 8);

  const float al = attnl[w * 16 + m];
  const float ar = attnr[w * 16 + m];

  // stage feat tile (16 x 128 fp32) coalesced into padded LDS
  const float4* gF = (const float4*)(feat + (size_t)b * 16 * 128);
  #pragma unroll
  for (int i = 0; i < 2; ++i) {
    const int idx = i * 256 + t;          // 0..511 float4s
    const int node = idx >> 5, off = idx & 31;
    float4 v = make_float4(0.f, 0.f, 0.f, 0.f);
    if (b * 16 + node < N) v = gF[idx];
    *(float4*)(sF + node * 132 + off * 4) = v;
  }
  __syncthreads();

  // K loop: LDS fp32 -> bf16 A-frag -> MFMA
  f32x4v acc = {0.f, 0.f, 0.f, 0.f};
  const float* arow = sF + m * 132 + q * 8;
  #pragma unroll
  for (int kc = 0; kc < 4; ++kc) {
    const float4 a0 = *(const float4*)(arow + kc * 32);
    const float4 a1 = *(const float4*)(arow + kc * 32 + 4);
    bf16x8 af;
    af[0] = f2bfs(a0.x); af[1] = f2bfs(a0.y);
    af[2] = f2bfs(a0.z); af[3] = f2bfs(a0.w);
    af[4] = f2bfs(a1.x); af[5] = f2bfs(a1.y);
    af[6] = f2bfs(a1.z); af[7] = f2bfs(a1.w);
    acc = __builtin_amdgcn_mfma_f32_16x16x32_bf16(af, bfr[kc], acc, 0, 0, 0);
  }

  // epilogue: h store, el/er (16-lane reductions), block maxima
  float mel = -1e30f, mer = -1e30f;
  #pragma unroll
  for (int r = 0; r < 4; ++r) {
    const int node = q * 4 + r;
    const int gn = b * 16 + node;
    const float hv = acc[r];
    float evl = hv * al;
    float evr = hv * ar;
    #pragma unroll
    for (int off = 8; off >= 1; off >>= 1) {
      evl += __shfl_xor(evl, off, 16);
      evr += __shfl_xor(evr, off, 16);
    }
    if (gn < N) {
      h_out[(size_t)gn * 64 + w * 16 + m] = f2bf(hv);
      if (m == 0) {
        el[gn * 4 + w] = evl;
        er[gn * 4 + w] = evr;
      }
    }
    mel = fmaxf(mel, evl);
    mer = fmaxf(mer, evr);
  }
  // cross-quad wave max, then per-block store (NO global atomics)
  mel = fmaxf(mel, __shfl_xor(mel, 16, 64));
  mel = fmaxf(mel, __shfl_xor(mel, 32, 64));
  mer = fmaxf(mer, __shfl_xor(mer, 16, 64));
  mer = fmaxf(mer, __shfl_xor(mer, 32, 64));
  if (l == 0) { wmax[w * 2] = mel; wmax[w * 2 + 1] = mer; }
  __syncthreads();
  if (t == 0) {
    float a = fmaxf(fmaxf(wmax[0], wmax[2]), fmaxf(wmax[4], wmax[6]));
    float c = fmaxf(fmaxf(wmax[1], wmax[3]), fmaxf(wmax[5], wmax[7]));
    blockmax2[b * 2] = a;
    blockmax2[b * 2 + 1] = c;
  }
}

// ---------------------------------------------------------------------------
// Target-degree histogram.
// ---------------------------------------------------------------------------
__global__ __launch_bounds__(256) void gat_deg(
    const int* __restrict__ trg, int* __restrict__ deg, int E)
{
  const int e = blockIdx.x * 256 + threadIdx.x;
  if (e < E) atomicAdd(&deg[trg[e]], 1);
}

// ---------------------------------------------------------------------------
// Hierarchical exclusive scan of deg -> rowoff[N+1]
// ---------------------------------------------------------------------------
__global__ __launch_bounds__(256) void scan_part(
    const int* __restrict__ deg, int* __restrict__ partial, int N)
{
  const int i = blockIdx.x * 256 + threadIdx.x;
  int v = (i < N) ? deg[i] : 0;
  #pragma unroll
  for (int off = 32; off >= 1; off >>= 1) v += __shfl_xor(v, off, 64);
  __shared__ int wv[4];
  if ((threadIdx.x & 63) == 0) wv[threadIdx.x >> 6] = v;
  __syncthreads();
  if (threadIdx.x == 0) partial[blockIdx.x] = wv[0] + wv[1] + wv[2] + wv[3];
}

// scan_top also max-reduces blockmax2[2*nbL] -> single scalar M (upper bound)
__global__ __launch_bounds__(512) void scan_top(
    const int* __restrict__ partial, int n, int* __restrict__ bpref,
    const float* __restrict__ blockmax2, int nbL, float* __restrict__ gmaxM)
{
  const int t = threadIdx.x;
  const int lane = t & 63, w = t >> 6;
  int v = (t < n) ? partial[t] : 0;
  const int orig = v;
  #pragma unroll
  for (int d = 1; d < 64; d <<= 1) {
    int u = __shfl_up(v, d, 64);
    if (lane >= d) v += u;
  }
  __shared__ int ws[8];
  if (lane == 63) ws[w] = v;
  __syncthreads();
  int off = 0;
  for (int i = 0; i < w; ++i) off += ws[i];
  if (t < n) bpref[t] = off + v - orig;

  // ---- global-max reduce (softmax shift bound) ----
  float mel = -1e30f, mer = -1e30f;
  for (int i = t; i < nbL; i += 512) {
    mel = fmaxf(mel, blockmax2[i * 2]);
    mer = fmaxf(mer, blockmax2[i * 2 + 1]);
  }
  #pragma unroll
  for (int o = 32; o >= 1; o >>= 1) {
    mel = fmaxf(mel, __shfl_xor(mel, o, 64));
    mer = fmaxf(mer, __shfl_xor(mer, o, 64));
  }
  __shared__ float wm[16];
  if (lane == 0) { wm[w * 2] = mel; wm[w * 2 + 1] = mer; }
  __syncthreads();
  if (t == 0) {
    float a = -1e30f, c = -1e30f;
    for (int i = 0; i < 8; ++i) {
      a = fmaxf(a, wm[i * 2]);
      c = fmaxf(c, wm[i * 2 + 1]);
    }
    gmaxM[0] = fmaxf(0.f, a + c);
  }
}

__global__ __launch_bounds__(256) void scan_final(
    const int* __restrict__ deg, const int* __restrict__ bpref,
    int* __restrict__ rowoff, int N)
{
  const int i = blockIdx.x * 256 + threadIdx.x;
  const int lane = threadIdx.x & 63, w = threadIdx.x >> 6;
  int v = (i < N) ? deg[i] : 0;
  const int orig = v;
  #pragma unroll
  for (int d = 1; d < 64; d <<= 1) {
    int u = __shfl_up(v, d, 64);
    if (lane >= d) v += u;
  }
  __shared__ int ws[4];
  if (lane == 63) ws[w] = v;
  __syncthreads();
  int off = 0;
  for (int j = 0; j < w; ++j) off += ws[j];
  const int excl = bpref[blockIdx.x] + off + v - orig;
  if (i <= N) rowoff[i] = excl;
}

// ---------------------------------------------------------------------------
// Counting-sort edges by target; store SOURCE node id.
// ---------------------------------------------------------------------------
__global__ __launch_bounds__(256) void gat_scatter(
    const int* __restrict__ src, const int* __restrict__ trg,
    const int* __restrict__ rowoff, int* __restrict__ cursor,
    int* __restrict__ csrsrc, int E)
{
  const int e = blockIdx.x * 256 + threadIdx.x;
  if (e >= E) return;
  const int ti = trg[e];
  const int pos = atomicAdd(&cursor[ti], 1);
  csrsrc[rowoff[ti] + pos] = src[e];
}

// ---------------------------------------------------------------------------
// Aggregation: one wave per target node, fp32 output.
// ---------------------------------------------------------------------------
__global__ __launch_bounds__(256) void gat_agg(
    const int* __restrict__ csrsrc, const int* __restrict__ rowoff,
    const float* __restrict__ el, const float* __restrict__ er,
    const ushort_t* __restrict__ hbf, const float* __restrict__ gmaxM,
    float* __restrict__ out, int N)
{
  const int l = threadIdx.x & 63;
  const int n = blockIdx.x * 4 + (threadIdx.x >> 6);
  if (n >= N) return;
  const int hd = l >> 4;
  const int start = rowoff[n];
  const int end = rowoff[n + 1];
  const float M = gmaxM[0];
  const float ern = er[n * 4 + hd];

  float acc = 0.f, dacc = 0.f;
  for (int base = start; base < end; base += 64) {
    const int cnt = min(64, end - base);
    int sn = 0;
    if (l < cnt) sn = csrsrc[base + l];
    for (int j = 0; j < cnt; ++j) {
      const int snj = __shfl(sn, j, 64);
      const float s = leaky(el[snj * 4 + hd] + ern);
      const float p = __expf(s - M);
      dacc += p;
      acc += bf2f(hbf[(size_t)snj * 64 + l]) * p;
    }
  }
  out[(size_t)n * 64 + l] = acc / (dacc + 1e-16f);
}

// ---------------------------------------------------------------------------
extern "C" void kernel_launch(void* const* d_in, const int* in_sizes, int n_in,
                              void* d_out, int out_size, void* d_ws, size_t ws_size,
                              hipStream_t stream) {
  const float* feat  = (const float*)d_in[0];
  const float* W     = (const float*)d_in[1];
  const float* attnl = (const float*)d_in[2];
  const float* attnr = (const float*)d_in[3];
  const int* src = (const int*)d_in[4];
  const int* trg = (const int*)d_in[5];
  float* out = (float*)d_out;

  const int N = in_sizes[0] / 128;  // 100000
  const int E = in_sizes[4];        // 1600000

  char* p = (char*)d_ws;
  auto take = [&](size_t bytes) -> char* {
    char* r = p;
    p += (bytes + 255) & ~(size_t)255;
    return r;
  };
  ushort_t* h_bf  = (ushort_t*)take((size_t)N * 64 * 2); // 12.8 MB
  float* el       = (float*)take((size_t)N * 16);        // 1.6 MB
  float* er       = (float*)take((size_t)N * 16);        // 1.6 MB
  int* deg        = (int*)take((size_t)N * 4);
  int* rowoff     = (int*)take((size_t)(N + 1) * 4);
  int* cursor     = (int*)take((size_t)N * 4);
  int* csrsrc     = (int*)take((size_t)E * 4);           // 6.4 MB
  ushort_t* wfrag = (ushort_t*)take(4 * 4 * 64 * 8 * 2); // 16 KB
  const int nbL = (N + 15) / 16;                         // 6250 (linear blocks)
  const int nbE = (E + 255) / 256;                       // 6250
  const int nbS = (N + 255) / 256;                       // 391
  float* blockmax2 = (float*)take((size_t)nbL * 2 * 4);
  float* gmaxM    = (float*)take(256);
  int* partial    = (int*)take((size_t)nbS * 4);
  int* bpref      = (int*)take((size_t)nbS * 4);

  hipMemsetAsync(deg, 0, (size_t)N * 4, stream);
  hipMemsetAsync(cursor, 0, (size_t)N * 4, stream);

  gat_packw<<<1, 256, 0, stream>>>(W, wfrag);
  gat_deg<<<nbE, 256, 0, stream>>>(trg, deg, E);
  gat_linear<<<nbL, 256, 0, stream>>>(feat, wfrag, attnl, attnr,
                                      h_bf, el, er, blockmax2, N);
  scan_part<<<nbS, 256, 0, stream>>>(deg, partial, N);
  scan_top<<<1, 512, 0, stream>>>(partial, nbS, bpref, blockmax2, nbL, gmaxM);
  scan_final<<<nbS, 256, 0, stream>>>(deg, bpref, rowoff, N);
  gat_scatter<<<nbE, 256, 0, stream>>>(src, trg, rowoff, cursor, csrsrc, E);
  gat_agg<<<(N + 3) / 4, 256, 0, stream>>>(csrsrc, rowoff, el, er, h_bf,
                                           gmaxM, out, N);
}

// Round 6
// 326.413 us; speedup vs baseline: 1.5835x; 1.1708x over previous
//
#include <hip/hip_runtime.h>

typedef unsigned short ushort_t;
typedef __attribute__((ext_vector_type(8))) short bf16x8;
typedef __attribute__((ext_vector_type(4))) float f32x4v;

static __device__ __forceinline__ float bf2f(ushort_t u) {
  union { unsigned int i; float f; } v; v.i = ((unsigned int)u) << 16; return v.f;
}
static __device__ __forceinline__ ushort_t f2bf(float f) {
  union { float f; unsigned int i; } v; v.f = f;
  unsigned int r = v.i + 0x7FFFu + ((v.i >> 16) & 1u);
  return (ushort_t)(r >> 16);
}
static __device__ __forceinline__ short f2bfs(float f) {
  return (short)f2bf(f);
}
static __device__ __forceinline__ float leaky(float s) {
  return s > 0.f ? s : 0.2f * s;
}

// ---------------------------------------------------------------------------
// Pack W (fp32 [128][64]) into bf16 B-fragments for mfma_f32_16x16x32_bf16.
// ---------------------------------------------------------------------------
__global__ __launch_bounds__(256) void gat_packw(
    const float* __restrict__ W, ushort_t* __restrict__ wfrag)
{
  const int t = threadIdx.x;
  const int w = t >> 6, l = t & 63;
  const int q = l >> 4, n = l & 15;
  #pragma unroll
  for (int kc = 0; kc < 4; ++kc) {
    #pragma unroll
    for (int j = 0; j < 8; ++j) {
      const int k = kc * 32 + q * 8 + j;
      wfrag[(((w * 4 + kc) * 64) + l) * 8 + j] = f2bf(W[k * 64 + w * 16 + n]);
    }
  }
}

// ---------------------------------------------------------------------------
// Kernel A (MFMA): h = feat @ W -> bf16 h, fp32 el/er, per-block maxima.
// FUSED: target-degree histogram (grid covers E = nbL*256 edges).
// ---------------------------------------------------------------------------
__global__ __launch_bounds__(256) void gat_linear(
    const float* __restrict__ feat, const ushort_t* __restrict__ wfrag,
    const float* __restrict__ attnl, const float* __restrict__ attnr,
    const int* __restrict__ trg, int* __restrict__ deg, int E,
    ushort_t* __restrict__ h_out, float* __restrict__ el, float* __restrict__ er,
    float* __restrict__ blockmax2, int N)
{
  __shared__ float sF[16 * 132];   // padded stride 132 floats (8.4 KB)
  __shared__ float wmax[8];
  const int t = threadIdx.x;
  const int b = blockIdx.x;
  const int w = t >> 6, l = t & 63;
  const int q = l >> 4, m = l & 15;

  // fused degree histogram: one edge per thread
  const int e = b * 256 + t;
  if (e < E) atomicAdd(&deg[trg[e]], 1);

  // B-fragments from L2/L3-resident packed W
  bf16x8 bfr[4];
  #pragma unroll
  for (int kc = 0; kc < 4; ++kc)
    bfr[kc] = *(const bf16x8*)(wfrag + (((w * 4 + kc) * 64) + l) * 8);

  const float al = attnl[w * 16 + m];
  const float ar = attnr[w * 16 + m];

  // stage feat tile (16 x 128 fp32) coalesced into padded LDS
  const float4* gF = (const float4*)(feat + (size_t)b * 16 * 128);
  #pragma unroll
  for (int i = 0; i < 2; ++i) {
    const int idx = i * 256 + t;
    const int node = idx >> 5, off = idx & 31;
    float4 v = make_float4(0.f, 0.f, 0.f, 0.f);
    if (b * 16 + node < N) v = gF[idx];
    *(float4*)(sF + node * 132 + off * 4) = v;
  }
  __syncthreads();

  f32x4v acc = {0.f, 0.f, 0.f, 0.f};
  const float* arow = sF + m * 132 + q * 8;
  #pragma unroll
  for (int kc = 0; kc < 4; ++kc) {
    const float4 a0 = *(const float4*)(arow + kc * 32);
    const float4 a1 = *(const float4*)(arow + kc * 32 + 4);
    bf16x8 af;
    af[0] = f2bfs(a0.x); af[1] = f2bfs(a0.y);
    af[2] = f2bfs(a0.z); af[3] = f2bfs(a0.w);
    af[4] = f2bfs(a1.x); af[5] = f2bfs(a1.y);
    af[6] = f2bfs(a1.z); af[7] = f2bfs(a1.w);
    acc = __builtin_amdgcn_mfma_f32_16x16x32_bf16(af, bfr[kc], acc, 0, 0, 0);
  }

  float mel = -1e30f, mer = -1e30f;
  #pragma unroll
  for (int r = 0; r < 4; ++r) {
    const int node = q * 4 + r;
    const int gn = b * 16 + node;
    const float hv = acc[r];
    float evl = hv * al;
    float evr = hv * ar;
    #pragma unroll
    for (int off = 8; off >= 1; off >>= 1) {
      evl += __shfl_xor(evl, off, 16);
      evr += __shfl_xor(evr, off, 16);
    }
    if (gn < N) {
      h_out[(size_t)gn * 64 + w * 16 + m] = f2bf(hv);
      if (m == 0) {
        el[gn * 4 + w] = evl;
        er[gn * 4 + w] = evr;
      }
    }
    mel = fmaxf(mel, evl);
    mer = fmaxf(mer, evr);
  }
  mel = fmaxf(mel, __shfl_xor(mel, 16, 64));
  mel = fmaxf(mel, __shfl_xor(mel, 32, 64));
  mer = fmaxf(mer, __shfl_xor(mer, 16, 64));
  mer = fmaxf(mer, __shfl_xor(mer, 32, 64));
  if (l == 0) { wmax[w * 2] = mel; wmax[w * 2 + 1] = mer; }
  __syncthreads();
  if (t == 0) {
    float a = fmaxf(fmaxf(wmax[0], wmax[2]), fmaxf(wmax[4], wmax[6]));
    float c = fmaxf(fmaxf(wmax[1], wmax[3]), fmaxf(wmax[5], wmax[7]));
    blockmax2[b * 2] = a;
    blockmax2[b * 2 + 1] = c;
  }
}

// ---------------------------------------------------------------------------
// Hierarchical exclusive scan of deg -> rowoff[N+1]
// ---------------------------------------------------------------------------
__global__ __launch_bounds__(256) void scan_part(
    const int* __restrict__ deg, int* __restrict__ partial, int N)
{
  const int i = blockIdx.x * 256 + threadIdx.x;
  int v = (i < N) ? deg[i] : 0;
  #pragma unroll
  for (int off = 32; off >= 1; off >>= 1) v += __shfl_xor(v, off, 64);
  __shared__ int wv[4];
  if ((threadIdx.x & 63) == 0) wv[threadIdx.x >> 6] = v;
  __syncthreads();
  if (threadIdx.x == 0) partial[blockIdx.x] = wv[0] + wv[1] + wv[2] + wv[3];
}

// scan_top also max-reduces blockmax2 -> M = max(0, maxel+maxer)
__global__ __launch_bounds__(512) void scan_top(
    const int* __restrict__ partial, int n, int* __restrict__ bpref,
    const float* __restrict__ blockmax2, int nbL, float* __restrict__ gmaxM)
{
  const int t = threadIdx.x;
  const int lane = t & 63, w = t >> 6;
  int v = (t < n) ? partial[t] : 0;
  const int orig = v;
  #pragma unroll
  for (int d = 1; d < 64; d <<= 1) {
    int u = __shfl_up(v, d, 64);
    if (lane >= d) v += u;
  }
  __shared__ int ws[8];
  if (lane == 63) ws[w] = v;
  __syncthreads();
  int off = 0;
  for (int i = 0; i < w; ++i) off += ws[i];
  if (t < n) bpref[t] = off + v - orig;

  float mel = -1e30f, mer = -1e30f;
  for (int i = t; i < nbL; i += 512) {
    mel = fmaxf(mel, blockmax2[i * 2]);
    mer = fmaxf(mer, blockmax2[i * 2 + 1]);
  }
  #pragma unroll
  for (int o = 32; o >= 1; o >>= 1) {
    mel = fmaxf(mel, __shfl_xor(mel, o, 64));
    mer = fmaxf(mer, __shfl_xor(mer, o, 64));
  }
  __shared__ float wm[16];
  if (lane == 0) { wm[w * 2] = mel; wm[w * 2 + 1] = mer; }
  __syncthreads();
  if (t == 0) {
    float a = -1e30f, c = -1e30f;
    for (int i = 0; i < 8; ++i) {
      a = fmaxf(a, wm[i * 2]);
      c = fmaxf(c, wm[i * 2 + 1]);
    }
    gmaxM[0] = fmaxf(0.f, a + c);
  }
}

__global__ __launch_bounds__(256) void scan_final(
    const int* __restrict__ deg, const int* __restrict__ bpref,
    int* __restrict__ rowoff, int N)
{
  const int i = blockIdx.x * 256 + threadIdx.x;
  const int lane = threadIdx.x & 63, w = threadIdx.x >> 6;
  int v = (i < N) ? deg[i] : 0;
  const int orig = v;
  #pragma unroll
  for (int d = 1; d < 64; d <<= 1) {
    int u = __shfl_up(v, d, 64);
    if (lane >= d) v += u;
  }
  __shared__ int ws[4];
  if (lane == 63) ws[w] = v;
  __syncthreads();
  int off = 0;
  for (int j = 0; j < w; ++j) off += ws[j];
  const int excl = bpref[blockIdx.x] + off + v - orig;
  if (i <= N) rowoff[i] = excl;
}

// ---------------------------------------------------------------------------
// Counting-sort edges by target; store SOURCE node id.
// ---------------------------------------------------------------------------
__global__ __launch_bounds__(256) void gat_scatter(
    const int* __restrict__ src, const int* __restrict__ trg,
    const int* __restrict__ rowoff, int* __restrict__ cursor,
    int* __restrict__ csrsrc, int E)
{
  const int e = blockIdx.x * 256 + threadIdx.x;
  if (e >= E) return;
  const int ti = trg[e];
  const int pos = atomicAdd(&cursor[ti], 1);
  csrsrc[rowoff[ti] + pos] = src[e];
}

// ---------------------------------------------------------------------------
// Aggregation: one wave per target node.
// Prefetch phase (parallel over lanes): p4 = exp(leaky(el4[src]+er4[n]) - M)
// staged to per-wave LDS. Serial loop: shfl src + ushort h load + LDS p
// broadcast + fma, with 4 independent accumulators (ILP).
// ---------------------------------------------------------------------------
__global__ __launch_bounds__(256) void gat_agg(
    const int* __restrict__ csrsrc, const int* __restrict__ rowoff,
    const float4* __restrict__ el4, const float4* __restrict__ er4,
    const ushort_t* __restrict__ hbf, const float* __restrict__ gmaxM,
    float* __restrict__ out, int N)
{
  __shared__ float sP[4 * 64 * 4];    // per-wave p staging (4 KB)
  const int t = threadIdx.x;
  const int l = t & 63;
  const int w = t >> 6;
  const int n = blockIdx.x * 4 + w;
  if (n >= N) return;
  const int hd = l >> 4;
  const int start = rowoff[n];
  const int end = rowoff[n + 1];
  const float M = gmaxM[0];
  const float4 ern = er4[n];
  float* sPw = sP + w * 256;

  float a0 = 0.f, a1 = 0.f, a2 = 0.f, a3 = 0.f;
  float dacc = 0.f;

  for (int base = start; base < end; base += 64) {
    const int cnt = min(64, end - base);
    int sn = 0;
    float4 pv = make_float4(0.f, 0.f, 0.f, 0.f);
    if (l < cnt) {
      sn = csrsrc[base + l];
      const float4 a = el4[sn];
      pv.x = __expf(leaky(a.x + ern.x) - M);
      pv.y = __expf(leaky(a.y + ern.y) - M);
      pv.z = __expf(leaky(a.z + ern.z) - M);
      pv.w = __expf(leaky(a.w + ern.w) - M);
    }
    *(float4*)(sPw + l * 4) = pv;   // per-wave region; same-wave RAW, no barrier

    int j = 0;
    for (; j + 4 <= cnt; j += 4) {
      const int s0 = __shfl(sn, j,     64);
      const int s1 = __shfl(sn, j + 1, 64);
      const int s2 = __shfl(sn, j + 2, 64);
      const int s3 = __shfl(sn, j + 3, 64);
      const float p0 = sPw[(j)     * 4 + hd];
      const float p1 = sPw[(j + 1) * 4 + hd];
      const float p2 = sPw[(j + 2) * 4 + hd];
      const float p3 = sPw[(j + 3) * 4 + hd];
      a0 += bf2f(hbf[(size_t)s0 * 64 + l]) * p0;
      a1 += bf2f(hbf[(size_t)s1 * 64 + l]) * p1;
      a2 += bf2f(hbf[(size_t)s2 * 64 + l]) * p2;
      a3 += bf2f(hbf[(size_t)s3 * 64 + l]) * p3;
      dacc += (p0 + p1) + (p2 + p3);
    }
    for (; j < cnt; ++j) {
      const int s0 = __shfl(sn, j, 64);
      const float p0 = sPw[j * 4 + hd];
      a0 += bf2f(hbf[(size_t)s0 * 64 + l]) * p0;
      dacc += p0;
    }
  }
  const float acc = (a0 + a1) + (a2 + a3);
  out[(size_t)n * 64 + l] = acc / (dacc + 1e-16f);
}

// ---------------------------------------------------------------------------
extern "C" void kernel_launch(void* const* d_in, const int* in_sizes, int n_in,
                              void* d_out, int out_size, void* d_ws, size_t ws_size,
                              hipStream_t stream) {
  const float* feat  = (const float*)d_in[0];
  const float* W     = (const float*)d_in[1];
  const float* attnl = (const float*)d_in[2];
  const float* attnr = (const float*)d_in[3];
  const int* src = (const int*)d_in[4];
  const int* trg = (const int*)d_in[5];
  float* out = (float*)d_out;

  const int N = in_sizes[0] / 128;  // 100000
  const int E = in_sizes[4];        // 1600000

  char* p = (char*)d_ws;
  auto take = [&](size_t bytes) -> char* {
    char* r = p;
    p += (bytes + 255) & ~(size_t)255;
    return r;
  };
  ushort_t* h_bf  = (ushort_t*)take((size_t)N * 64 * 2); // 12.8 MB
  float* el       = (float*)take((size_t)N * 16);        // 1.6 MB
  float* er       = (float*)take((size_t)N * 16);        // 1.6 MB
  int* deg        = (int*)take((size_t)N * 4);
  int* rowoff     = (int*)take((size_t)(N + 1) * 4);
  int* cursor     = (int*)take((size_t)N * 4);
  int* csrsrc     = (int*)take((size_t)E * 4);           // 6.4 MB
  ushort_t* wfrag = (ushort_t*)take(4 * 4 * 64 * 8 * 2); // 16 KB
  const int nbL = (N + 15) / 16;                         // 6250
  const int nbE = (E + 255) / 256;                       // 6250
  const int nbS = (N + 255) / 256;                       // 391
  float* blockmax2 = (float*)take((size_t)nbL * 2 * 4);
  float* gmaxM    = (float*)take(256);
  int* partial    = (int*)take((size_t)nbS * 4);
  int* bpref      = (int*)take((size_t)nbS * 4);

  hipMemsetAsync(deg, 0, (size_t)N * 4, stream);
  hipMemsetAsync(cursor, 0, (size_t)N * 4, stream);

  gat_packw<<<1, 256, 0, stream>>>(W, wfrag);
  gat_linear<<<nbL, 256, 0, stream>>>(feat, wfrag, attnl, attnr,
                                      trg, deg, E,
                                      h_bf, el, er, blockmax2, N);
  scan_part<<<nbS, 256, 0, stream>>>(deg, partial, N);
  scan_top<<<1, 512, 0, stream>>>(partial, nbS, bpref, blockmax2, nbL, gmaxM);
  scan_final<<<nbS, 256, 0, stream>>>(deg, bpref, rowoff, N);
  gat_scatter<<<nbE, 256, 0, stream>>>(src, trg, rowoff, cursor, csrsrc, E);
  gat_agg<<<(N + 3) / 4, 256, 0, stream>>>(csrsrc, rowoff, (const float4*)el,
                                           (const float4*)er, h_bf,
                                           gmaxM, out, N);
}

// Round 7
// 236.399 us; speedup vs baseline: 2.1865x; 1.3808x over previous
//
#include <hip/hip_runtime.h>

typedef unsigned short ushort_t;
typedef __attribute__((ext_vector_type(8))) short bf16x8;
typedef __attribute__((ext_vector_type(4))) float f32x4v;

#define EPB 8000   // edges per sort block

static __device__ __forceinline__ float bf2f(ushort_t u) {
  union { unsigned int i; float f; } v; v.i = ((unsigned int)u) << 16; return v.f;
}
static __device__ __forceinline__ ushort_t f2bf(float f) {
  union { float f; unsigned int i; } v; v.f = f;
  unsigned int r = v.i + 0x7FFFu + ((v.i >> 16) & 1u);
  return (ushort_t)(r >> 16);
}
static __device__ __forceinline__ short f2bfs(float f) {
  return (short)f2bf(f);
}
static __device__ __forceinline__ float leaky(float s) {
  return s > 0.f ? s : 0.2f * s;
}

// ---------------------------------------------------------------------------
// Pack W (fp32 [128][64]) into bf16 B-fragments for mfma_f32_16x16x32_bf16.
// ---------------------------------------------------------------------------
__global__ __launch_bounds__(256) void gat_packw(
    const float* __restrict__ W, ushort_t* __restrict__ wfrag)
{
  const int t = threadIdx.x;
  const int w = t >> 6, l = t & 63;
  const int q = l >> 4, n = l & 15;
  #pragma unroll
  for (int kc = 0; kc < 4; ++kc) {
    #pragma unroll
    for (int j = 0; j < 8; ++j) {
      const int k = kc * 32 + q * 8 + j;
      wfrag[(((w * 4 + kc) * 64) + l) * 8 + j] = f2bf(W[k * 64 + w * 16 + n]);
    }
  }
}

// ---------------------------------------------------------------------------
// Kernel A (MFMA): h = feat @ W -> bf16 h, fp32 el/er, per-block maxima.
// ---------------------------------------------------------------------------
__global__ __launch_bounds__(256) void gat_linear(
    const float* __restrict__ feat, const ushort_t* __restrict__ wfrag,
    const float* __restrict__ attnl, const float* __restrict__ attnr,
    ushort_t* __restrict__ h_out, float* __restrict__ el, float* __restrict__ er,
    float* __restrict__ blockmax2, int N)
{
  __shared__ float sF[16 * 132];
  __shared__ float wmax[8];
  const int t = threadIdx.x;
  const int b = blockIdx.x;
  const int w = t >> 6, l = t & 63;
  const int q = l >> 4, m = l & 15;

  bf16x8 bfr[4];
  #pragma unroll
  for (int kc = 0; kc < 4; ++kc)
    bfr[kc] = *(const bf16x8*)(wfrag + (((w * 4 + kc) * 64) + l) * 8);

  const float al = attnl[w * 16 + m];
  const float ar = attnr[w * 16 + m];

  const float4* gF = (const float4*)(feat + (size_t)b * 16 * 128);
  #pragma unroll
  for (int i = 0; i < 2; ++i) {
    const int idx = i * 256 + t;
    const int node = idx >> 5, off = idx & 31;
    float4 v = make_float4(0.f, 0.f, 0.f, 0.f);
    if (b * 16 + node < N) v = gF[idx];
    *(float4*)(sF + node * 132 + off * 4) = v;
  }
  __syncthreads();

  f32x4v acc = {0.f, 0.f, 0.f, 0.f};
  const float* arow = sF + m * 132 + q * 8;
  #pragma unroll
  for (int kc = 0; kc < 4; ++kc) {
    const float4 a0 = *(const float4*)(arow + kc * 32);
    const float4 a1 = *(const float4*)(arow + kc * 32 + 4);
    bf16x8 af;
    af[0] = f2bfs(a0.x); af[1] = f2bfs(a0.y);
    af[2] = f2bfs(a0.z); af[3] = f2bfs(a0.w);
    af[4] = f2bfs(a1.x); af[5] = f2bfs(a1.y);
    af[6] = f2bfs(a1.z); af[7] = f2bfs(a1.w);
    acc = __builtin_amdgcn_mfma_f32_16x16x32_bf16(af, bfr[kc], acc, 0, 0, 0);
  }

  float mel = -1e30f, mer = -1e30f;
  #pragma unroll
  for (int r = 0; r < 4; ++r) {
    const int node = q * 4 + r;
    const int gn = b * 16 + node;
    const float hv = acc[r];
    float evl = hv * al;
    float evr = hv * ar;
    #pragma unroll
    for (int off = 8; off >= 1; off >>= 1) {
      evl += __shfl_xor(evl, off, 16);
      evr += __shfl_xor(evr, off, 16);
    }
    if (gn < N) {
      h_out[(size_t)gn * 64 + w * 16 + m] = f2bf(hv);
      if (m == 0) {
        el[gn * 4 + w] = evl;
        er[gn * 4 + w] = evr;
      }
    }
    mel = fmaxf(mel, evl);
    mer = fmaxf(mer, evr);
  }
  mel = fmaxf(mel, __shfl_xor(mel, 16, 64));
  mel = fmaxf(mel, __shfl_xor(mel, 32, 64));
  mer = fmaxf(mer, __shfl_xor(mer, 16, 64));
  mer = fmaxf(mer, __shfl_xor(mer, 32, 64));
  if (l == 0) { wmax[w * 2] = mel; wmax[w * 2 + 1] = mer; }
  __syncthreads();
  if (t == 0) {
    float a = fmaxf(fmaxf(wmax[0], wmax[2]), fmaxf(wmax[4], wmax[6]));
    float c = fmaxf(fmaxf(wmax[1], wmax[3]), fmaxf(wmax[5], wmax[7]));
    blockmax2[b * 2] = a;
    blockmax2[b * 2 + 1] = c;
  }
}

// ---------------------------------------------------------------------------
// Sort P1: per-block LDS histogram over coarse buckets (trg>>9). No atomics
// to global; blockHist[blk][bkt] written coalesced.
// ---------------------------------------------------------------------------
__global__ __launch_bounds__(256) void bucket_hist(
    const int* __restrict__ trg, int E, int nbkt, int* __restrict__ blockHist)
{
  __shared__ int hist[256];
  const int t = threadIdx.x, b = blockIdx.x;
  hist[t] = 0;
  __syncthreads();
  const int start = b * EPB;
  const int end = min(start + EPB, E);
  for (int e = start + t; e < end; e += 256)
    atomicAdd(&hist[trg[e] >> 9], 1);
  __syncthreads();
  if (t < nbkt) blockHist[b * nbkt + t] = hist[t];
}

// ---------------------------------------------------------------------------
// Sort P2a: per-bucket column scan of blockHist -> in-place exclusive prefix,
// colTotal[bkt]. One wave per bucket.
// ---------------------------------------------------------------------------
__global__ __launch_bounds__(64) void bucket_scan(
    int* __restrict__ blockHist, int nb3, int nbkt, int* __restrict__ colTotal)
{
  const int b = blockIdx.x;
  const int l = threadIdx.x;
  int carry = 0;
  for (int r = 0; r * 64 < nb3; ++r) {
    const int i = r * 64 + l;
    int v = (i < nb3) ? blockHist[i * nbkt + b] : 0;
    int incl = v;
    #pragma unroll
    for (int d = 1; d < 64; d <<= 1) {
      int u = __shfl_up(incl, d, 64);
      if (l >= d) incl += u;
    }
    if (i < nb3) blockHist[i * nbkt + b] = carry + incl - v;
    carry += __shfl(incl, 63, 64);
  }
  if (l == 0) colTotal[b] = carry;
}

// ---------------------------------------------------------------------------
// Sort P2b: scan colTotal -> bucketBase; fused gmaxM reduction; rowoff[N]=E.
// ---------------------------------------------------------------------------
__global__ __launch_bounds__(256) void bucket_base(
    const int* __restrict__ colTotal, int nbkt, int* __restrict__ bucketBase,
    const float* __restrict__ blockmax2, int nbL, float* __restrict__ gmaxM,
    int* __restrict__ rowoff, int N, int E)
{
  const int t = threadIdx.x;
  const int l = t & 63, w = t >> 6;
  if (w == 0) {
    int carry = 0;
    for (int r = 0; r * 64 < nbkt; ++r) {
      const int i = r * 64 + l;
      int v = (i < nbkt) ? colTotal[i] : 0;
      int incl = v;
      #pragma unroll
      for (int d = 1; d < 64; d <<= 1) {
        int u = __shfl_up(incl, d, 64);
        if (l >= d) incl += u;
      }
      if (i < nbkt) bucketBase[i] = carry + incl - v;
      carry += __shfl(incl, 63, 64);
    }
    if (l == 0) { bucketBase[nbkt] = carry; rowoff[N] = E; }
  }
  float mel = -1e30f, mer = -1e30f;
  for (int i = t; i < nbL; i += 256) {
    mel = fmaxf(mel, blockmax2[i * 2]);
    mer = fmaxf(mer, blockmax2[i * 2 + 1]);
  }
  #pragma unroll
  for (int o = 32; o >= 1; o >>= 1) {
    mel = fmaxf(mel, __shfl_xor(mel, o, 64));
    mer = fmaxf(mer, __shfl_xor(mer, o, 64));
  }
  __shared__ float wm[8];
  if (l == 0) { wm[w * 2] = mel; wm[w * 2 + 1] = mer; }
  __syncthreads();
  if (t == 0) {
    float a = fmaxf(fmaxf(wm[0], wm[2]), fmaxf(wm[4], wm[6]));
    float c = fmaxf(fmaxf(wm[1], wm[3]), fmaxf(wm[5], wm[7]));
    gmaxM[0] = fmaxf(0.f, a + c);
  }
}

// ---------------------------------------------------------------------------
// Sort P3: deterministic scatter into coarse buckets. Positions come from
// bucketBase + per-(block,bucket) prefix + LDS cursor: NO global atomics.
// Payload packed: (src<<9) | localTrg.
// ---------------------------------------------------------------------------
__global__ __launch_bounds__(256) void bucket_scatter(
    const int* __restrict__ src, const int* __restrict__ trg, int E, int nbkt,
    const int* __restrict__ blockHist, const int* __restrict__ bucketBase,
    unsigned int* __restrict__ binned)
{
  __shared__ int cursor[256];
  const int t = threadIdx.x, b = blockIdx.x;
  if (t < nbkt) cursor[t] = bucketBase[t] + blockHist[b * nbkt + t];
  __syncthreads();
  const int start = b * EPB;
  const int end = min(start + EPB, E);
  for (int e = start + t; e < end; e += 256) {
    const int ti = trg[e];
    const int bkt = ti >> 9;
    const int pos = atomicAdd(&cursor[bkt], 1);
    binned[pos] = ((unsigned int)src[e] << 9) | (unsigned int)(ti & 511);
  }
}

// ---------------------------------------------------------------------------
// Sort P4: one block per bucket. LDS hist over 512 targets -> rowoff;
// LDS-cursor placement of src into the bucket's contiguous csrsrc segment.
// All writes to a segment come from ONE block/XCD -> L2 merges lines.
// ---------------------------------------------------------------------------
__global__ __launch_bounds__(512) void fine_scatter(
    const unsigned int* __restrict__ binned, const int* __restrict__ bucketBase,
    int* __restrict__ rowoff, int* __restrict__ csrsrc, int N)
{
  __shared__ int cnt[512];
  __shared__ int ws[8];
  const int t = threadIdx.x, b = blockIdx.x;
  const int l = t & 63, w = t >> 6;
  const int base = bucketBase[b];
  const int end = bucketBase[b + 1];
  cnt[t] = 0;
  __syncthreads();
  for (int i = base + t; i < end; i += 512)
    atomicAdd(&cnt[binned[i] & 511u], 1);
  __syncthreads();
  // block exclusive scan of cnt[512]
  const int v = cnt[t];
  int incl = v;
  #pragma unroll
  for (int d = 1; d < 64; d <<= 1) {
    int u = __shfl_up(incl, d, 64);
    if (l >= d) incl += u;
  }
  if (l == 63) ws[w] = incl;
  __syncthreads();
  int woff = 0;
  for (int i = 0; i < w; ++i) woff += ws[i];
  const int loc = woff + incl - v;   // exclusive prefix
  cnt[t] = loc;                      // own slot only; becomes cursor
  const int gt = b * 512 + t;
  if (gt < N) rowoff[gt] = base + loc;
  __syncthreads();
  for (int i = base + t; i < end; i += 512) {
    const unsigned int pv = binned[i];
    const int lt = (int)(pv & 511u);
    const int pos = base + atomicAdd(&cnt[lt], 1);
    csrsrc[pos] = (int)(pv >> 9);
  }
}

// ---------------------------------------------------------------------------
// Aggregation: one wave per target node (unchanged from round 6).
// ---------------------------------------------------------------------------
__global__ __launch_bounds__(256) void gat_agg(
    const int* __restrict__ csrsrc, const int* __restrict__ rowoff,
    const float4* __restrict__ el4, const float4* __restrict__ er4,
    const ushort_t* __restrict__ hbf, const float* __restrict__ gmaxM,
    float* __restrict__ out, int N)
{
  __shared__ float sP[4 * 64 * 4];
  const int t = threadIdx.x;
  const int l = t & 63;
  const int w = t >> 6;
  const int n = blockIdx.x * 4 + w;
  if (n >= N) return;
  const int hd = l >> 4;
  const int start = rowoff[n];
  const int end = rowoff[n + 1];
  const float M = gmaxM[0];
  const float4 ern = er4[n];
  float* sPw = sP + w * 256;

  float a0 = 0.f, a1 = 0.f, a2 = 0.f, a3 = 0.f;
  float dacc = 0.f;

  for (int base = start; base < end; base += 64) {
    const int cnt = min(64, end - base);
    int sn = 0;
    float4 pv = make_float4(0.f, 0.f, 0.f, 0.f);
    if (l < cnt) {
      sn = csrsrc[base + l];
      const float4 a = el4[sn];
      pv.x = __expf(leaky(a.x + ern.x) - M);
      pv.y = __expf(leaky(a.y + ern.y) - M);
      pv.z = __expf(leaky(a.z + ern.z) - M);
      pv.w = __expf(leaky(a.w + ern.w) - M);
    }
    *(float4*)(sPw + l * 4) = pv;

    int j = 0;
    for (; j + 4 <= cnt; j += 4) {
      const int s0 = __shfl(sn, j,     64);
      const int s1 = __shfl(sn, j + 1, 64);
      const int s2 = __shfl(sn, j + 2, 64);
      const int s3 = __shfl(sn, j + 3, 64);
      const float p0 = sPw[(j)     * 4 + hd];
      const float p1 = sPw[(j + 1) * 4 + hd];
      const float p2 = sPw[(j + 2) * 4 + hd];
      const float p3 = sPw[(j + 3) * 4 + hd];
      a0 += bf2f(hbf[(size_t)s0 * 64 + l]) * p0;
      a1 += bf2f(hbf[(size_t)s1 * 64 + l]) * p1;
      a2 += bf2f(hbf[(size_t)s2 * 64 + l]) * p2;
      a3 += bf2f(hbf[(size_t)s3 * 64 + l]) * p3;
      dacc += (p0 + p1) + (p2 + p3);
    }
    for (; j < cnt; ++j) {
      const int s0 = __shfl(sn, j, 64);
      const float p0 = sPw[j * 4 + hd];
      a0 += bf2f(hbf[(size_t)s0 * 64 + l]) * p0;
      dacc += p0;
    }
  }
  const float acc = (a0 + a1) + (a2 + a3);
  out[(size_t)n * 64 + l] = acc / (dacc + 1e-16f);
}

// ---------------------------------------------------------------------------
extern "C" void kernel_launch(void* const* d_in, const int* in_sizes, int n_in,
                              void* d_out, int out_size, void* d_ws, size_t ws_size,
                              hipStream_t stream) {
  const float* feat  = (const float*)d_in[0];
  const float* W     = (const float*)d_in[1];
  const float* attnl = (const float*)d_in[2];
  const float* attnr = (const float*)d_in[3];
  const int* src = (const int*)d_in[4];
  const int* trg = (const int*)d_in[5];
  float* out = (float*)d_out;

  const int N = in_sizes[0] / 128;  // 100000
  const int E = in_sizes[4];        // 1600000

  const int nbL  = (N + 15) / 16;        // 6250 linear blocks
  const int nbkt = (N + 511) >> 9;       // 196 coarse buckets
  const int nb3  = (E + EPB - 1) / EPB;  // 200 sort blocks

  char* p = (char*)d_ws;
  auto take = [&](size_t bytes) -> char* {
    char* r = p;
    p += (bytes + 255) & ~(size_t)255;
    return r;
  };
  ushort_t* h_bf  = (ushort_t*)take((size_t)N * 64 * 2); // 12.8 MB
  float* el       = (float*)take((size_t)N * 16);        // 1.6 MB
  float* er       = (float*)take((size_t)N * 16);        // 1.6 MB
  int* rowoff     = (int*)take((size_t)(N + 1) * 4);
  int* csrsrc     = (int*)take((size_t)E * 4);           // 6.4 MB
  unsigned int* binned = (unsigned int*)take((size_t)E * 4); // 6.4 MB
  ushort_t* wfrag = (ushort_t*)take(4 * 4 * 64 * 8 * 2); // 16 KB
  int* blockHist  = (int*)take((size_t)nb3 * nbkt * 4);  // 157 KB
  int* colTotal   = (int*)take((size_t)nbkt * 4);
  int* bucketBase = (int*)take((size_t)(nbkt + 1) * 4);
  float* blockmax2 = (float*)take((size_t)nbL * 2 * 4);
  float* gmaxM    = (float*)take(256);

  gat_packw<<<1, 256, 0, stream>>>(W, wfrag);
  gat_linear<<<nbL, 256, 0, stream>>>(feat, wfrag, attnl, attnr,
                                      h_bf, el, er, blockmax2, N);
  bucket_hist<<<nb3, 256, 0, stream>>>(trg, E, nbkt, blockHist);
  bucket_scan<<<nbkt, 64, 0, stream>>>(blockHist, nb3, nbkt, colTotal);
  bucket_base<<<1, 256, 0, stream>>>(colTotal, nbkt, bucketBase,
                                     blockmax2, nbL, gmaxM, rowoff, N, E);
  bucket_scatter<<<nb3, 256, 0, stream>>>(src, trg, E, nbkt, blockHist,
                                          bucketBase, binned);
  fine_scatter<<<nbkt, 512, 0, stream>>>(binned, bucketBase, rowoff, csrsrc, N);
  gat_agg<<<(N + 3) / 4, 256, 0, stream>>>(csrsrc, rowoff, (const float4*)el,
                                           (const float4*)er, h_bf,
                                           gmaxM, out, N);
}

// Round 8
// 224.857 us; speedup vs baseline: 2.2987x; 1.0513x over previous
//
#include <hip/hip_runtime.h>

typedef unsigned short ushort_t;
typedef __attribute__((ext_vector_type(8))) short bf16x8;
typedef __attribute__((ext_vector_type(4))) float f32x4v;

#define EPB 8000   // edges per sort block

static __device__ __forceinline__ float bf2f(ushort_t u) {
  union { unsigned int i; float f; } v; v.i = ((unsigned int)u) << 16; return v.f;
}
static __device__ __forceinline__ ushort_t f2bf(float f) {
  union { float f; unsigned int i; } v; v.f = f;
  unsigned int r = v.i + 0x7FFFu + ((v.i >> 16) & 1u);
  return (ushort_t)(r >> 16);
}
static __device__ __forceinline__ float leaky(float s) {
  return s > 0.f ? s : 0.2f * s;
}

// ---------------------------------------------------------------------------
// FUSED: block nb3 packs W_ext into B-fragments; blocks 0..nb3-1 do the
// coarse-bucket histogram.
// W_ext = [W | W@attn_l | W@attn_r | 0] -> 5 tiles of 16 cols. Tile 4:
// cols 0-3 = el heads, cols 4-7 = er heads, 8-15 = zero. So el/er fall out
// of the same MFMA K-loop as h (el = feat @ (W attn_l)).
// ---------------------------------------------------------------------------
__global__ __launch_bounds__(256) void packw_hist(
    const float* __restrict__ W, const float* __restrict__ attnl,
    const float* __restrict__ attnr, ushort_t* __restrict__ wfrag,
    const int* __restrict__ trg, int E, int nbkt,
    int* __restrict__ blockHist, int nb3)
{
  const int b = blockIdx.x;
  const int t = threadIdx.x;
  if (b == nb3) {
    const int kc = t >> 6, l = t & 63;
    const int q = l >> 4, n = l & 15;
    #pragma unroll
    for (int tile = 0; tile < 5; ++tile) {
      #pragma unroll
      for (int j = 0; j < 8; ++j) {
        const int k = kc * 32 + q * 8 + j;
        float v = 0.f;
        if (tile < 4) {
          v = W[k * 64 + tile * 16 + n];
        } else if (n < 4) {
          for (int f = 0; f < 16; ++f)
            v += W[k * 64 + n * 16 + f] * attnl[n * 16 + f];
        } else if (n < 8) {
          const int hd = n - 4;
          for (int f = 0; f < 16; ++f)
            v += W[k * 64 + hd * 16 + f] * attnr[hd * 16 + f];
        }
        wfrag[((tile * 4 + kc) * 64 + l) * 8 + j] = f2bf(v);
      }
    }
    return;
  }
  __shared__ int hist[256];
  hist[t] = 0;
  __syncthreads();
  const int start = b * EPB;
  const int end = min(start + EPB, E);
  for (int e = start + t; e < end; e += 256)
    atomicAdd(&hist[trg[e] >> 9], 1);
  __syncthreads();
  if (t < nbkt) blockHist[b * nbkt + t] = hist[t];
}

// ---------------------------------------------------------------------------
// Per-bucket column scan of blockHist -> in-place exclusive prefix + total.
// ---------------------------------------------------------------------------
__global__ __launch_bounds__(64) void bucket_scan(
    int* __restrict__ blockHist, int nb3, int nbkt, int* __restrict__ colTotal)
{
  const int b = blockIdx.x;
  const int l = threadIdx.x;
  int carry = 0;
  for (int r = 0; r * 64 < nb3; ++r) {
    const int i = r * 64 + l;
    int v = (i < nb3) ? blockHist[i * nbkt + b] : 0;
    int incl = v;
    #pragma unroll
    for (int d = 1; d < 64; d <<= 1) {
      int u = __shfl_up(incl, d, 64);
      if (l >= d) incl += u;
    }
    if (i < nb3) blockHist[i * nbkt + b] = carry + incl - v;
    carry += __shfl(incl, 63, 64);
  }
  if (l == 0) colTotal[b] = carry;
}

// ---------------------------------------------------------------------------
// Scan colTotal -> bucketBase; rowoff[N]=E.
// ---------------------------------------------------------------------------
__global__ __launch_bounds__(64) void bucket_base(
    const int* __restrict__ colTotal, int nbkt, int* __restrict__ bucketBase,
    int* __restrict__ rowoff, int N, int E)
{
  const int l = threadIdx.x;
  int carry = 0;
  for (int r = 0; r * 64 < nbkt; ++r) {
    const int i = r * 64 + l;
    int v = (i < nbkt) ? colTotal[i] : 0;
    int incl = v;
    #pragma unroll
    for (int d = 1; d < 64; d <<= 1) {
      int u = __shfl_up(incl, d, 64);
      if (l >= d) incl += u;
    }
    if (i < nbkt) bucketBase[i] = carry + incl - v;
    carry += __shfl(incl, 63, 64);
  }
  if (l == 0) { bucketBase[nbkt] = carry; rowoff[N] = E; }
}

// ---------------------------------------------------------------------------
// Deterministic coarse scatter (no global atomics); payload (src<<9)|localTrg.
// ---------------------------------------------------------------------------
__global__ __launch_bounds__(256) void bucket_scatter(
    const int* __restrict__ src, const int* __restrict__ trg, int E, int nbkt,
    const int* __restrict__ blockHist, const int* __restrict__ bucketBase,
    unsigned int* __restrict__ binned)
{
  __shared__ int cursor[256];
  const int t = threadIdx.x, b = blockIdx.x;
  if (t < nbkt) cursor[t] = bucketBase[t] + blockHist[b * nbkt + t];
  __syncthreads();
  const int start = b * EPB;
  const int end = min(start + EPB, E);
  for (int e = start + t; e < end; e += 256) {
    const int ti = trg[e];
    const int bkt = ti >> 9;
    const int pos = atomicAdd(&cursor[bkt], 1);
    binned[pos] = ((unsigned int)src[e] << 9) | (unsigned int)(ti & 511);
  }
}

// ---------------------------------------------------------------------------
// Kernel A (MFMA): h_ext = feat @ W_ext. 64 nodes/block; wave w owns nodes
// w*16..w*16+15 across all 5 col-tiles. feat staged bf16 in LDS (pad 136).
// Tile 4 yields el/er directly in C-layout -> no shuffle reductions.
// ---------------------------------------------------------------------------
__global__ __launch_bounds__(256) void gat_linear(
    const float* __restrict__ feat, const ushort_t* __restrict__ wfrag,
    ushort_t* __restrict__ h_out, float* __restrict__ el, float* __restrict__ er,
    float* __restrict__ blockmax2, int N)
{
  __shared__ ushort_t sFb[64 * 136];   // 17.4 KB
  __shared__ float wmax[8];
  const int t = threadIdx.x;
  const int b = blockIdx.x;
  const int w = t >> 6, l = t & 63;
  const int q = l >> 4, m = l & 15;

  // stage feat (64 x 128 fp32 -> bf16), coalesced float4 loads
  const float4* gF = (const float4*)(feat + (size_t)b * 64 * 128);
  #pragma unroll
  for (int i = 0; i < 8; ++i) {
    const int idx = i * 256 + t;
    const int node = idx >> 5, off = idx & 31;
    float4 v = make_float4(0.f, 0.f, 0.f, 0.f);
    if (b * 64 + node < N) v = gF[idx];
    unsigned int p0 = ((unsigned int)f2bf(v.y) << 16) | f2bf(v.x);
    unsigned int p1 = ((unsigned int)f2bf(v.w) << 16) | f2bf(v.z);
    *(uint2*)(sFb + node * 136 + off * 4) = make_uint2(p0, p1);
  }
  __syncthreads();

  // A-fragments: 4 K-chunks, one ds_read_b128 each
  bf16x8 a[4];
  const ushort_t* arow = sFb + (w * 16 + m) * 136 + q * 8;
  #pragma unroll
  for (int kc = 0; kc < 4; ++kc)
    a[kc] = *(const bf16x8*)(arow + kc * 32);

  // tiles 0..3: h columns
  #pragma unroll
  for (int tile = 0; tile < 4; ++tile) {
    f32x4v acc = {0.f, 0.f, 0.f, 0.f};
    #pragma unroll
    for (int kc = 0; kc < 4; ++kc) {
      bf16x8 bfr = *(const bf16x8*)(wfrag + ((tile * 4 + kc) * 64 + l) * 8);
      acc = __builtin_amdgcn_mfma_f32_16x16x32_bf16(a[kc], bfr, acc, 0, 0, 0);
    }
    #pragma unroll
    for (int r = 0; r < 4; ++r) {
      const int gn = b * 64 + w * 16 + q * 4 + r;
      if (gn < N) h_out[(size_t)gn * 64 + tile * 16 + m] = f2bf(acc[r]);
    }
  }

  // tile 4: el (cols 0-3) / er (cols 4-7)
  f32x4v acc4 = {0.f, 0.f, 0.f, 0.f};
  #pragma unroll
  for (int kc = 0; kc < 4; ++kc) {
    bf16x8 bfr = *(const bf16x8*)(wfrag + ((4 * 4 + kc) * 64 + l) * 8);
    acc4 = __builtin_amdgcn_mfma_f32_16x16x32_bf16(a[kc], bfr, acc4, 0, 0, 0);
  }
  float mel = -1e30f, mer = -1e30f;
  #pragma unroll
  for (int r = 0; r < 4; ++r) {
    const int gn = b * 64 + w * 16 + q * 4 + r;
    const float v = acc4[r];
    if (m < 4) {
      if (gn < N) el[gn * 4 + m] = v;
      mel = fmaxf(mel, v);
    } else if (m < 8) {
      if (gn < N) er[gn * 4 + (m - 4)] = v;
      mer = fmaxf(mer, v);
    }
  }
  #pragma unroll
  for (int o = 1; o <= 32; o <<= 1) {
    mel = fmaxf(mel, __shfl_xor(mel, o, 64));
    mer = fmaxf(mer, __shfl_xor(mer, o, 64));
  }
  if (l == 0) { wmax[w * 2] = mel; wmax[w * 2 + 1] = mer; }
  __syncthreads();
  if (t == 0) {
    float aa = fmaxf(fmaxf(wmax[0], wmax[2]), fmaxf(wmax[4], wmax[6]));
    float cc = fmaxf(fmaxf(wmax[1], wmax[3]), fmaxf(wmax[5], wmax[7]));
    blockmax2[b * 2] = aa;
    blockmax2[b * 2 + 1] = cc;
  }
}

// ---------------------------------------------------------------------------
// Fine sort (one block per bucket) + block 0 reduces blockmax2 -> gmaxM.
// ---------------------------------------------------------------------------
__global__ __launch_bounds__(512) void fine_scatter(
    const unsigned int* __restrict__ binned, const int* __restrict__ bucketBase,
    int* __restrict__ rowoff, int* __restrict__ csrsrc, int N,
    const float* __restrict__ blockmax2, int nbL, float* __restrict__ gmaxM)
{
  __shared__ int cnt[512];
  __shared__ int ws[8];
  __shared__ float wmg[16];
  const int t = threadIdx.x, b = blockIdx.x;
  const int l = t & 63, w = t >> 6;
  const int base = bucketBase[b];
  const int end = bucketBase[b + 1];
  cnt[t] = 0;
  if (b == 0) {
    float mel = -1e30f, mer = -1e30f;
    for (int i = t; i < nbL; i += 512) {
      mel = fmaxf(mel, blockmax2[i * 2]);
      mer = fmaxf(mer, blockmax2[i * 2 + 1]);
    }
    #pragma unroll
    for (int o = 1; o <= 32; o <<= 1) {
      mel = fmaxf(mel, __shfl_xor(mel, o, 64));
      mer = fmaxf(mer, __shfl_xor(mer, o, 64));
    }
    if (l == 0) { wmg[w * 2] = mel; wmg[w * 2 + 1] = mer; }
  }
  __syncthreads();
  if (b == 0 && t == 0) {
    float aa = -1e30f, cc = -1e30f;
    for (int i = 0; i < 8; ++i) {
      aa = fmaxf(aa, wmg[i * 2]);
      cc = fmaxf(cc, wmg[i * 2 + 1]);
    }
    gmaxM[0] = fmaxf(0.f, aa + cc);
  }
  for (int i = base + t; i < end; i += 512)
    atomicAdd(&cnt[binned[i] & 511u], 1);
  __syncthreads();
  const int v = cnt[t];
  int incl = v;
  #pragma unroll
  for (int d = 1; d < 64; d <<= 1) {
    int u = __shfl_up(incl, d, 64);
    if (l >= d) incl += u;
  }
  if (l == 63) ws[w] = incl;
  __syncthreads();
  int woff = 0;
  for (int i = 0; i < w; ++i) woff += ws[i];
  const int loc = woff + incl - v;
  cnt[t] = loc;
  const int gt = b * 512 + t;
  if (gt < N) rowoff[gt] = base + loc;
  __syncthreads();
  for (int i = base + t; i < end; i += 512) {
    const unsigned int pv = binned[i];
    const int lt = (int)(pv & 511u);
    const int pos = base + atomicAdd(&cnt[lt], 1);
    csrsrc[pos] = (int)(pv >> 9);
  }
}

// ---------------------------------------------------------------------------
// Aggregation: one wave per target node. Prefetch p per edge (parallel over
// lanes, staged in per-wave LDS); serial loop 8-unrolled (8 h-rows in
// flight); denominator accumulated vectorized + one end reduction.
// ---------------------------------------------------------------------------
__global__ __launch_bounds__(256) void gat_agg(
    const int* __restrict__ csrsrc, const int* __restrict__ rowoff,
    const float4* __restrict__ el4, const float4* __restrict__ er4,
    const ushort_t* __restrict__ hbf, const float* __restrict__ gmaxM,
    float* __restrict__ out, int N)
{
  __shared__ float sP[4 * 64 * 4];
  const int t = threadIdx.x;
  const int l = t & 63;
  const int w = t >> 6;
  const int n = blockIdx.x * 4 + w;
  if (n >= N) return;
  const int hd = l >> 4;
  const int start = rowoff[n];
  const int end = rowoff[n + 1];
  const float M = gmaxM[0];
  const float4 ern = er4[n];
  float* sPw = sP + w * 256;

  float a0 = 0.f, a1 = 0.f, a2 = 0.f, a3 = 0.f;
  float a4 = 0.f, a5 = 0.f, a6 = 0.f, a7 = 0.f;
  float4 dsum = make_float4(0.f, 0.f, 0.f, 0.f);

  for (int base = start; base < end; base += 64) {
    const int cnt = min(64, end - base);
    int sn = 0;
    float4 pv = make_float4(0.f, 0.f, 0.f, 0.f);
    if (l < cnt) {
      sn = csrsrc[base + l];
      const float4 a = el4[sn];
      pv.x = __expf(leaky(a.x + ern.x) - M);
      pv.y = __expf(leaky(a.y + ern.y) - M);
      pv.z = __expf(leaky(a.z + ern.z) - M);
      pv.w = __expf(leaky(a.w + ern.w) - M);
    }
    dsum.x += pv.x; dsum.y += pv.y; dsum.z += pv.z; dsum.w += pv.w;
    *(float4*)(sPw + l * 4) = pv;

    int j = 0;
    for (; j + 8 <= cnt; j += 8) {
      const int s0 = __shfl(sn, j,     64);
      const int s1 = __shfl(sn, j + 1, 64);
      const int s2 = __shfl(sn, j + 2, 64);
      const int s3 = __shfl(sn, j + 3, 64);
      const int s4 = __shfl(sn, j + 4, 64);
      const int s5 = __shfl(sn, j + 5, 64);
      const int s6 = __shfl(sn, j + 6, 64);
      const int s7 = __shfl(sn, j + 7, 64);
      a0 += bf2f(hbf[(size_t)s0 * 64 + l]) * sPw[(j)     * 4 + hd];
      a1 += bf2f(hbf[(size_t)s1 * 64 + l]) * sPw[(j + 1) * 4 + hd];
      a2 += bf2f(hbf[(size_t)s2 * 64 + l]) * sPw[(j + 2) * 4 + hd];
      a3 += bf2f(hbf[(size_t)s3 * 64 + l]) * sPw[(j + 3) * 4 + hd];
      a4 += bf2f(hbf[(size_t)s4 * 64 + l]) * sPw[(j + 4) * 4 + hd];
      a5 += bf2f(hbf[(size_t)s5 * 64 + l]) * sPw[(j + 5) * 4 + hd];
      a6 += bf2f(hbf[(size_t)s6 * 64 + l]) * sPw[(j + 6) * 4 + hd];
      a7 += bf2f(hbf[(size_t)s7 * 64 + l]) * sPw[(j + 7) * 4 + hd];
    }
    for (; j < cnt; ++j) {
      const int s0 = __shfl(sn, j, 64);
      a0 += bf2f(hbf[(size_t)s0 * 64 + l]) * sPw[j * 4 + hd];
    }
  }
  #pragma unroll
  for (int o = 1; o <= 32; o <<= 1) {
    dsum.x += __shfl_xor(dsum.x, o, 64);
    dsum.y += __shfl_xor(dsum.y, o, 64);
    dsum.z += __shfl_xor(dsum.z, o, 64);
    dsum.w += __shfl_xor(dsum.w, o, 64);
  }
  const float dacc = (hd == 0) ? dsum.x : (hd == 1) ? dsum.y
                   : (hd == 2) ? dsum.z : dsum.w;
  const float acc = ((a0 + a1) + (a2 + a3)) + ((a4 + a5) + (a6 + a7));
  out[(size_t)n * 64 + l] = acc / (dacc + 1e-16f);
}

// ---------------------------------------------------------------------------
extern "C" void kernel_launch(void* const* d_in, const int* in_sizes, int n_in,
                              void* d_out, int out_size, void* d_ws, size_t ws_size,
                              hipStream_t stream) {
  const float* feat  = (const float*)d_in[0];
  const float* W     = (const float*)d_in[1];
  const float* attnl = (const float*)d_in[2];
  const float* attnr = (const float*)d_in[3];
  const int* src = (const int*)d_in[4];
  const int* trg = (const int*)d_in[5];
  float* out = (float*)d_out;

  const int N = in_sizes[0] / 128;  // 100000
  const int E = in_sizes[4];        // 1600000

  const int nbL  = (N + 63) / 64;        // 1563 linear blocks
  const int nbkt = (N + 511) >> 9;       // 196 coarse buckets
  const int nb3  = (E + EPB - 1) / EPB;  // 200 sort blocks

  char* p = (char*)d_ws;
  auto take = [&](size_t bytes) -> char* {
    char* r = p;
    p += (bytes + 255) & ~(size_t)255;
    return r;
  };
  ushort_t* h_bf  = (ushort_t*)take((size_t)N * 64 * 2); // 12.8 MB
  float* el       = (float*)take((size_t)N * 16);        // 1.6 MB
  float* er       = (float*)take((size_t)N * 16);        // 1.6 MB
  int* rowoff     = (int*)take((size_t)(N + 1) * 4);
  int* csrsrc     = (int*)take((size_t)E * 4);           // 6.4 MB
  unsigned int* binned = (unsigned int*)take((size_t)E * 4); // 6.4 MB
  ushort_t* wfrag = (ushort_t*)take(5 * 4 * 64 * 8 * 2); // 20.5 KB
  int* blockHist  = (int*)take((size_t)nb3 * nbkt * 4);  // 157 KB
  int* colTotal   = (int*)take((size_t)nbkt * 4);
  int* bucketBase = (int*)take((size_t)(nbkt + 1) * 4);
  float* blockmax2 = (float*)take((size_t)nbL * 2 * 4);
  float* gmaxM    = (float*)take(256);

  packw_hist<<<nb3 + 1, 256, 0, stream>>>(W, attnl, attnr, wfrag,
                                          trg, E, nbkt, blockHist, nb3);
  bucket_scan<<<nbkt, 64, 0, stream>>>(blockHist, nb3, nbkt, colTotal);
  bucket_base<<<1, 64, 0, stream>>>(colTotal, nbkt, bucketBase, rowoff, N, E);
  bucket_scatter<<<nb3, 256, 0, stream>>>(src, trg, E, nbkt, blockHist,
                                          bucketBase, binned);
  gat_linear<<<nbL, 256, 0, stream>>>(feat, wfrag, h_bf, el, er,
                                      blockmax2, N);
  fine_scatter<<<nbkt, 512, 0, stream>>>(binned, bucketBase, rowoff, csrsrc,
                                         N, blockmax2, nbL, gmaxM);
  gat_agg<<<(N + 3) / 4, 256, 0, stream>>>(csrsrc, rowoff, (const float4*)el,
                                           (const float4*)er, h_bf,
                                           gmaxM, out, N);
}